// Round 8
// baseline (731.607 us; speedup 1.0000x reference)
//
#include <hip/hip_runtime.h>
#include <math.h>

#define SELU_ALPHA 1.6732632423543772f
#define SELU_SCALE 1.0507009873554805f

#define NBLK 512          // partition blocks (E divides exactly: 512*3125)
#define MAXBKT 512        // static LDS sizing; actual NBKT = ceil(N/256)

typedef __attribute__((ext_vector_type(8))) short bf16x8;
typedef __attribute__((ext_vector_type(4))) float f32x4;

__device__ __forceinline__ float selu_f(float x) {
    return SELU_SCALE * (x > 0.f ? x : SELU_ALPHA * expm1f(x));
}

__device__ __forceinline__ float bf2f(unsigned short u) {
    return __uint_as_float(((unsigned)u) << 16);
}
__device__ __forceinline__ unsigned short f2bf(float f) {
    unsigned u = __float_as_uint(f);
    unsigned r = (u + 0x7fffu + ((u >> 16) & 1u)) >> 16;
    return (unsigned short)r;
}

// physical XCD id [measured: learn_hip m09 — returns 0..7 on MI355X]
__device__ __forceinline__ int get_xcd() {
    unsigned v;
    asm volatile("s_getreg_b32 %0, hwreg(HW_REG_XCC_ID)" : "=s"(v));
    return (int)(v & 7);
}

__global__ void norm_kernel(const int* __restrict__ deg, float* __restrict__ norm, int n) {
    int i = blockIdx.x * blockDim.x + threadIdx.x;
    if (i >= n) return;
    norm[i] = 1.f / sqrtf(fmaxf((float)deg[i], 1.f));
}

// ---- exclusive scan (3 kernels), in-place safe ----
#define SCAN_B 1024

__global__ __launch_bounds__(256) void scan_block_sums(const int* __restrict__ in,
                                                       int* __restrict__ bsums, int n) {
    __shared__ int s[256];
    int b = blockIdx.x, t = threadIdx.x;
    int base = b * SCAN_B;
    int sum = 0;
    for (int i = t; i < SCAN_B; i += 256) {
        int idx = base + i;
        sum += (idx < n) ? in[idx] : 0;
    }
    s[t] = sum; __syncthreads();
    for (int off = 128; off > 0; off >>= 1) {
        if (t < off) s[t] += s[t + off];
        __syncthreads();
    }
    if (t == 0) bsums[b] = s[0];
}

__global__ __launch_bounds__(256) void scan_bsums(int* __restrict__ bsums, int nb) {
    __shared__ int s[256];
    __shared__ int carry_s;
    int t = threadIdx.x;
    if (t == 0) carry_s = 0;
    __syncthreads();
    for (int base = 0; base < nb; base += 256) {
        int idx = base + t;
        int v = (idx < nb) ? bsums[idx] : 0;
        s[t] = v; __syncthreads();
        for (int off = 1; off < 256; off <<= 1) {
            int x = (t >= off) ? s[t - off] : 0;
            __syncthreads();
            s[t] += x;
            __syncthreads();
        }
        int incl = s[t];
        int excl = incl - v;
        int c = carry_s;
        __syncthreads();
        if (idx < nb) bsums[idx] = c + excl;
        if (t == 255) carry_s = c + incl;
        __syncthreads();
    }
}

__global__ __launch_bounds__(256) void scan_apply(const int* __restrict__ in,
                                                  const int* __restrict__ boffs,
                                                  int* __restrict__ out, int n) {
    __shared__ int s[256];
    int b = blockIdx.x, t = threadIdx.x;
    int idx0 = b * SCAN_B + t * 4;
    int v[4]; int tsum = 0;
    #pragma unroll
    for (int k = 0; k < 4; ++k) {
        int idx = idx0 + k;
        v[k] = (idx < n) ? in[idx] : 0;
        tsum += v[k];
    }
    s[t] = tsum; __syncthreads();
    for (int off = 1; off < 256; off <<= 1) {
        int x = (t >= off) ? s[t - off] : 0;
        __syncthreads();
        s[t] += x;
        __syncthreads();
    }
    int run = s[t] - tsum + boffs[b];
    #pragma unroll
    for (int k = 0; k < 4; ++k) {
        int idx = idx0 + k;
        if (idx < n) out[idx] = run;
        run += v[k];
    }
}

// ---- K1: per-block coarse histograms of dst>>8 and src>>8 (LDS atomics only) ----
__global__ __launch_bounds__(256) void coarse_hist_kernel(
        const int* __restrict__ src, const int* __restrict__ dst,
        int* __restrict__ cntD, int* __restrict__ cntS, int E, int nbkt) {
    __shared__ int hD[MAXBKT];
    __shared__ int hS[MAXBKT];
    int bb = blockIdx.x, t = threadIdx.x;
    for (int k = t; k < MAXBKT; k += 256) { hD[k] = 0; hS[k] = 0; }
    __syncthreads();
    int chunk = E / NBLK;                 // exact
    int beg = bb * chunk, end = beg + chunk;
    for (int i = beg + t; i < end; i += 256) {
        atomicAdd(&hD[((unsigned)dst[i]) >> 8], 1);
        atomicAdd(&hS[((unsigned)src[i]) >> 8], 1);
    }
    __syncthreads();
    for (int k = t; k < nbkt; k += 256) {
        cntD[k * NBLK + bb] = hD[k];
        cntS[k * NBLK + bb] = hS[k];
    }
}

// ---- K2: scatter edges into dst-buckets (pairs) and src values into src-buckets ----
__global__ __launch_bounds__(256) void scatter_kernel(
        const int* __restrict__ src, const int* __restrict__ dst,
        const int* __restrict__ cntD, const int* __restrict__ cntS,
        uint2* __restrict__ pairs, int* __restrict__ sbuf, int E, int nbkt) {
    __shared__ int cD[MAXBKT];
    __shared__ int cS[MAXBKT];
    int bb = blockIdx.x, t = threadIdx.x;
    for (int k = t; k < nbkt; k += 256) {
        cD[k] = cntD[k * NBLK + bb];
        cS[k] = cntS[k * NBLK + bb];
    }
    __syncthreads();
    int chunk = E / NBLK;
    int beg = bb * chunk, end = beg + chunk;
    for (int i = beg + t; i < end; i += 256) {
        unsigned s = (unsigned)src[i], d = (unsigned)dst[i];
        int pD = atomicAdd(&cD[d >> 8], 1);
        pairs[pD] = make_uint2(s, d);
        int pS = atomicAdd(&cS[s >> 8], 1);
        sbuf[pS] = (int)s;
    }
}

// ---- K3a: per-bucket exact histogram of src values -> deg_out ----
__global__ __launch_bounds__(256) void bucket_deg_kernel(
        const int* __restrict__ sbuf, const int* __restrict__ cntS,
        int* __restrict__ deg_out, int N, int E, int nbkt) {
    __shared__ int hist[256];
    int b = blockIdx.x, t = threadIdx.x;
    int base = cntS[b * NBLK];
    int end = (b + 1 < nbkt) ? cntS[(b + 1) * NBLK] : E;
    hist[t] = 0; __syncthreads();
    for (int i = base + t; i < end; i += 256)
        atomicAdd(&hist[sbuf[i] & 255], 1);
    __syncthreads();
    int node = (b << 8) + t;
    if (node < N) deg_out[node] = hist[t];
}

// ---- K3b: per-bucket CSR build: row_start, deg_in, csr_src ----
__global__ __launch_bounds__(256) void bucket_csr_kernel(
        const uint2* __restrict__ pairs, const int* __restrict__ cntD,
        int* __restrict__ row_start, int* __restrict__ deg_in,
        int* __restrict__ csr_src, int N, int E, int nbkt) {
    __shared__ int hist[256];
    __shared__ int sc[256];
    __shared__ int cur[256];
    int b = blockIdx.x, t = threadIdx.x;
    int base = cntD[b * NBLK];
    int end = (b + 1 < nbkt) ? cntD[(b + 1) * NBLK] : E;
    hist[t] = 0; __syncthreads();
    for (int i = base + t; i < end; i += 256)
        atomicAdd(&hist[pairs[i].y & 255], 1);
    __syncthreads();
    int v = hist[t];
    sc[t] = v; __syncthreads();
    for (int off = 1; off < 256; off <<= 1) {
        int x = (t >= off) ? sc[t - off] : 0;
        __syncthreads();
        sc[t] += x;
        __syncthreads();
    }
    int ex = sc[t] - v;                  // exclusive in-bucket offset
    cur[t] = base + ex;
    int node = (b << 8) + t;
    if (node < N) { row_start[node] = base + ex; deg_in[node] = v; }
    __syncthreads();
    for (int i = base + t; i < end; i += 256) {
        uint2 p = pairs[i];
        int pos = atomicAdd(&cur[p.y & 255], 1);
        csr_src[pos] = (int)p.x;
    }
}

// ---- prep: feats [N][64] fp32 -> slice-major bf16 [8][N][8], prescaled by norm_out ----
__global__ void cvt_slice_kernel(const float* __restrict__ feats,
                                 const float* __restrict__ norm_out,
                                 unsigned short* __restrict__ outs, int N) {
    int i = blockIdx.x * blockDim.x + threadIdx.x;   // i = s*N + n
    if (i >= 8 * N) return;
    int s = i / N, n = i - s * N;
    float no = norm_out[n];
    const float* fp = feats + (size_t)n * 64 + s * 8;
    float4 a = *reinterpret_cast<const float4*>(fp);
    float4 b = *reinterpret_cast<const float4*>(fp + 4);
    unsigned short o[8] = { f2bf(a.x * no), f2bf(a.y * no), f2bf(a.z * no), f2bf(a.w * no),
                            f2bf(b.x * no), f2bf(b.y * no), f2bf(b.z * no), f2bf(b.w * no) };
    *reinterpret_cast<float4*>(outs + (size_t)i * 8) = *reinterpret_cast<float4*>(o);
}

// ---- prep: W [K][128] fp32 -> Wt [128][K] bf16 ----
__global__ void wt_transpose_kernel(const float* __restrict__ W, unsigned short* __restrict__ Wt,
                                    int K) {
    int i = blockIdx.x * blockDim.x + threadIdx.x;
    if (i >= 128 * K) return;
    int col = i / K, k = i % K;
    Wt[i] = f2bf(W[k * 128 + col]);
}

// ---- slice aggregate with physical-XCD work queue ----
// Work item = (slice, chunk). Block pulls from queue[its own XCD] first (steal-fallback
// over the others for correctness regardless of XCC_ID semantics). Slice s data (1.6 or
// 3.2 MB) is then gathered only by XCD s -> L2-resident. Streams (csr indices, row_start,
// deg) use nontemporal loads so they don't evict the slice.
template<int SF>   // feats per slice: 8 (FIN=64) or 16 (FIN=128)
__global__ __launch_bounds__(256) void slice_agg_kernel(
        const unsigned short* __restrict__ xs,     // [8][N][SF] bf16, prescaled by norm_out
        const int* __restrict__ row_start, const int* __restrict__ deg,
        const int* __restrict__ csr_src, const float* __restrict__ norm_in,
        unsigned short* __restrict__ aggs,         // [8][N][SF]
        int* __restrict__ q,                       // 8 counters, zeroed
        int C, int N) {
    const int LPN = SF / 8;            // lanes per node
    const int NPB = 256 / LPN;         // nodes per block
    __shared__ int s_item;
    if (threadIdx.x == 0) {
        int xcd = get_xcd();
        int item = -1;
        #pragma unroll
        for (int t = 0; t < 8; ++t) {
            int s = (xcd + t) & 7;
            int pos = atomicAdd(&q[s], 1);
            if (pos < C) { item = s * C + pos; break; }
        }
        s_item = item;
    }
    __syncthreads();
    int item = s_item;
    if (item < 0) return;
    int slice = item / C;
    int chunk = item - slice * C;

    int t = threadIdx.x;
    int n = chunk * NPB + t / LPN;
    int j = t % LPN;
    if (n >= N) return;
    const unsigned short* xb = xs + (size_t)slice * N * SF + j * 8;
    int beg = __builtin_nontemporal_load(row_start + n);
    int end = beg + __builtin_nontemporal_load(deg + n);
    float acc[8] = {0.f, 0.f, 0.f, 0.f, 0.f, 0.f, 0.f, 0.f};
    int e = beg;
    for (; e + 4 <= end; e += 4) {
        int s0 = __builtin_nontemporal_load(csr_src + e);
        int s1 = __builtin_nontemporal_load(csr_src + e + 1);
        int s2 = __builtin_nontemporal_load(csr_src + e + 2);
        int s3 = __builtin_nontemporal_load(csr_src + e + 3);
        float4 r0 = *reinterpret_cast<const float4*>(xb + (size_t)s0 * SF);
        float4 r1 = *reinterpret_cast<const float4*>(xb + (size_t)s1 * SF);
        float4 r2 = *reinterpret_cast<const float4*>(xb + (size_t)s2 * SF);
        float4 r3 = *reinterpret_cast<const float4*>(xb + (size_t)s3 * SF);
        const unsigned short* u0 = reinterpret_cast<const unsigned short*>(&r0);
        const unsigned short* u1 = reinterpret_cast<const unsigned short*>(&r1);
        const unsigned short* u2 = reinterpret_cast<const unsigned short*>(&r2);
        const unsigned short* u3 = reinterpret_cast<const unsigned short*>(&r3);
        #pragma unroll
        for (int k = 0; k < 8; ++k) acc[k] += bf2f(u0[k]);
        #pragma unroll
        for (int k = 0; k < 8; ++k) acc[k] += bf2f(u1[k]);
        #pragma unroll
        for (int k = 0; k < 8; ++k) acc[k] += bf2f(u2[k]);
        #pragma unroll
        for (int k = 0; k < 8; ++k) acc[k] += bf2f(u3[k]);
    }
    for (; e < end; ++e) {
        int s0 = __builtin_nontemporal_load(csr_src + e);
        float4 r0 = *reinterpret_cast<const float4*>(xb + (size_t)s0 * SF);
        const unsigned short* u0 = reinterpret_cast<const unsigned short*>(&r0);
        #pragma unroll
        for (int k = 0; k < 8; ++k) acc[k] += bf2f(u0[k]);
    }
    float nin = norm_in[n];
    unsigned short ov[8];
    #pragma unroll
    for (int k = 0; k < 8; ++k) ov[k] = f2bf(acc[k] * nin);
    f32x4* outp = reinterpret_cast<f32x4*>(
        aggs + (size_t)slice * N * SF + (size_t)n * SF + j * 8);
    __builtin_nontemporal_store(*reinterpret_cast<f32x4*>(ov), outp);
}

// ---- MFMA node GEMM (128x128 tile, 4 waves, 16x16x32 bf16) ----
template<int FIN, bool SELU, bool OUT_SLICED>
__global__ __launch_bounds__(256, 2) void gemm_mfma_kernel(
        const unsigned short* __restrict__ agg16,
        const unsigned short* __restrict__ Wt,     // [128][FIN] bf16
        const float* __restrict__ b,
        const float* __restrict__ norm_out,
        unsigned short* __restrict__ out,
        int N) {
    const int PAD = 8;
    const int LDA = FIN + PAD;
    const int CH = FIN / 8;        // 16B chunks per node-row
    const int CPS = CH / 8;        // chunks per slice (1 or 2)
    const int SF = CPS * 8;        // input feats per slice
    __shared__ unsigned short sA[128 * LDA];
    __shared__ unsigned short sW[128 * LDA];
    const int tid = threadIdx.x;
    const int wave = tid >> 6, lane = tid & 63;
    const int wr = (wave >> 1) * 64;
    const int wc = (wave & 1) * 64;
    const int n0 = blockIdx.x * 128;

    for (int i = tid; i < 128 * CH; i += 256) {
        int col = i & 127, kc = i >> 7;
        *reinterpret_cast<float4*>(&sW[col * LDA + kc * 8]) =
            *reinterpret_cast<const float4*>(&Wt[col * FIN + kc * 8]);
    }
    for (int i = tid; i < 128 * CH; i += 256) {
        int node = i & 127, kc = i >> 7;
        int n = n0 + node;
        float4 v = make_float4(0.f, 0.f, 0.f, 0.f);
        if (n < N) {
            int sl = kc / CPS, j = kc % CPS;
            v = *reinterpret_cast<const float4*>(
                agg16 + ((size_t)sl * N + n) * SF + j * 8);
        }
        *reinterpret_cast<float4*>(&sA[node * LDA + kc * 8]) = v;
    }
    __syncthreads();

    const int l16 = lane & 15;
    const int lk = (lane >> 4) * 8;
    f32x4 acc[4][4];
    #pragma unroll
    for (int mi = 0; mi < 4; ++mi)
        #pragma unroll
        for (int ci = 0; ci < 4; ++ci)
            acc[mi][ci] = (f32x4){0.f, 0.f, 0.f, 0.f};

    #pragma unroll
    for (int k0 = 0; k0 < FIN; k0 += 32) {
        bf16x8 a[4], w[4];
        #pragma unroll
        for (int mi = 0; mi < 4; ++mi)
            a[mi] = *reinterpret_cast<const bf16x8*>(&sA[(wr + mi * 16 + l16) * LDA + k0 + lk]);
        #pragma unroll
        for (int ci = 0; ci < 4; ++ci)
            w[ci] = *reinterpret_cast<const bf16x8*>(&sW[(wc + ci * 16 + l16) * LDA + k0 + lk]);
        #pragma unroll
        for (int mi = 0; mi < 4; ++mi)
            #pragma unroll
            for (int ci = 0; ci < 4; ++ci)
                acc[mi][ci] = __builtin_amdgcn_mfma_f32_16x16x32_bf16(
                    a[mi], w[ci], acc[mi][ci], 0, 0, 0);
    }

    // D frag: col = lane&15, row = (lane>>4)*4 + r
    const int rbase = (lane >> 4) * 4;
    #pragma unroll
    for (int ci = 0; ci < 4; ++ci) {
        int col = wc + ci * 16 + l16;
        float bias = b[col];
        int osl = col >> 4, of = col & 15;
        #pragma unroll
        for (int mi = 0; mi < 4; ++mi) {
            #pragma unroll
            for (int r = 0; r < 4; ++r) {
                int n = n0 + wr + mi * 16 + rbase + r;
                if (n < N) {
                    float v = acc[mi][ci][r] + bias;
                    if (SELU) v = selu_f(v);
                    if (OUT_SLICED) {
                        v *= norm_out[n];
                        out[((size_t)osl * N + n) * 16 + of] = f2bf(v);
                    } else {
                        out[(size_t)n * 128 + col] = f2bf(v);
                    }
                }
            }
        }
    }
}

// ---- graph range starts (node2graph sorted) ----
__global__ void graph_starts_kernel(const int* __restrict__ n2g, int* __restrict__ gstart,
                                    int N, int G) {
    int g = blockIdx.x * blockDim.x + threadIdx.x;
    if (g > G) return;
    int lo = 0, hi = N;
    while (lo < hi) {
        int mid = (lo + hi) >> 1;
        if (n2g[mid] < g) lo = mid + 1; else hi = mid;
    }
    gstart[g] = lo;
}

// ---- readout from bf16 y (row-major) ----
__global__ __launch_bounds__(128) void readout_kernel(
        const unsigned short* __restrict__ y, const int* __restrict__ gstart,
        float* __restrict__ gsum, int G) {
    int g = blockIdx.x;
    int o = threadIdx.x;
    if (g >= G) return;
    int beg = gstart[g], end = gstart[g + 1];
    float acc = 0.f;
    for (int n = beg; n < end; ++n)
        acc += bf2f(y[(size_t)n * 128 + o]);
    gsum[(size_t)g * 128 + o] = acc;
}

// ---- MLP head (fp32) ----
__global__ __launch_bounds__(256) void mlp1_kernel(
        const float* __restrict__ gsum, const float* __restrict__ fg,
        const float* __restrict__ W, const float* __restrict__ b,
        float* __restrict__ y1, int G) {
    int g = blockIdx.x;
    int o = threadIdx.x;
    if (g >= G) return;
    float acc = b[o];
    const float* in = gsum + (size_t)g * 128;
    #pragma unroll 8
    for (int k = 0; k < 128; ++k) acc += in[k] * W[k * 256 + o];
    const float* fgr = fg + (size_t)g * 3;
    acc += fgr[0] * W[128 * 256 + o];
    acc += fgr[1] * W[129 * 256 + o];
    acc += fgr[2] * W[130 * 256 + o];
    y1[(size_t)g * 256 + o] = selu_f(acc);
}

__global__ __launch_bounds__(128) void mlp2_kernel(
        const float* __restrict__ y1, const float* __restrict__ W,
        const float* __restrict__ b, float* __restrict__ y2, int G) {
    int g = blockIdx.x;
    int o = threadIdx.x;
    if (g >= G) return;
    float acc = b[o];
    const float* in = y1 + (size_t)g * 256;
    #pragma unroll 8
    for (int k = 0; k < 256; ++k) acc += in[k] * W[k * 128 + o];
    y2[(size_t)g * 128 + o] = selu_f(acc);
}

__global__ void mlp3_kernel(const float* __restrict__ y2, const float* __restrict__ W,
                            const float* __restrict__ b, float* __restrict__ out, int G) {
    int g = blockIdx.x * blockDim.x + threadIdx.x;
    if (g >= G) return;
    const float* in = y2 + (size_t)g * 128;
    float acc = b[0];
    #pragma unroll 8
    for (int k = 0; k < 128; ++k) acc += in[k] * W[k];
    out[g] = acc;
}

extern "C" void kernel_launch(void* const* d_in, const int* in_sizes, int n_in,
                              void* d_out, int out_size, void* d_ws, size_t ws_size,
                              hipStream_t stream) {
    const float* feats_node  = (const float*)d_in[0];
    const float* feats_graph = (const float*)d_in[1];
    const int*   src         = (const int*)d_in[2];
    const int*   dst         = (const int*)d_in[3];
    const int*   node2graph  = (const int*)d_in[4];
    const float* W1 = (const float*)d_in[5];
    const float* b1 = (const float*)d_in[6];
    const float* W2 = (const float*)d_in[7];
    const float* b2 = (const float*)d_in[8];
    const float* W3 = (const float*)d_in[9];
    const float* b3 = (const float*)d_in[10];
    const float* L1w = (const float*)d_in[11];
    const float* L1b = (const float*)d_in[12];
    const float* L2w = (const float*)d_in[13];
    const float* L2b = (const float*)d_in[14];
    const float* L3w = (const float*)d_in[15];
    const float* L3b = (const float*)d_in[16];

    const int N = in_sizes[0] / 64;
    const int G = in_sizes[1] / 3;
    const int E = in_sizes[2];
    const int NBKT = (N + 255) >> 8;
    const int nmat = NBKT * NBLK;
    const int NBsc = (nmat + SCAN_B - 1) / SCAN_B;

    // ---- workspace layout ----
    int* iws = (int*)d_ws;
    int* deg_out_i = iws;                      // N
    int* deg_in_i  = deg_out_i + N;            // N
    int* row_start = deg_in_i + N;             // N
    int* bsums     = row_start + N;            // 512
    int* q         = bsums + 512;              // 3*8 queue counters (pad 32)
    int* gstart    = q + 32;                   // G+8
    int* cntD      = gstart + (G + 8);         // nmat
    int* cntS      = cntD + nmat;              // nmat
    int* csr_src   = cntS + nmat;              // E

    float* norm_out = (float*)(csr_src + E);   // N
    float* norm_in  = norm_out + N;            // N

    unsigned short* feats16s = (unsigned short*)(norm_in + N);    // [8][N][8]  = N*64
    unsigned short* x16s     = feats16s + (size_t)N * 64;         // [8][N][16] = N*128
    unsigned short* agg16s   = x16s + (size_t)N * 128;            // [8][N][16] = N*128
    unsigned short* y16      = agg16s + (size_t)N * 128;          // [N][128]
    unsigned short* Wt1      = y16 + (size_t)N * 128;             // 128*64
    unsigned short* Wt2      = Wt1 + 128 * 64;                    // 128*128
    unsigned short* Wt3      = Wt2 + 128 * 128;                   // 128*128

    float* gsum = (float*)(Wt3 + 128 * 128);   // G*128
    float* y1   = gsum + (size_t)G * 128;      // G*256
    float* y2   = y1 + (size_t)G * 256;        // G*128

    // pairs/sbuf alias y16 (dead until layer-3 output)
    uint2* pairs = (uint2*)(((uintptr_t)y16 + 15) & ~(uintptr_t)15);  // E uint2
    int*   sbuf  = (int*)(pairs + E);                                  // E ints

    float* out = (float*)d_out;

    // ---- 0. weight transposes + queue zero ----
    (void)hipMemsetAsync(q, 0, 32 * sizeof(int), stream);
    wt_transpose_kernel<<<(128 * 64 + 255) / 256, 256, 0, stream>>>(W1, Wt1, 64);
    wt_transpose_kernel<<<(128 * 128 + 255) / 256, 256, 0, stream>>>(W2, Wt2, 128);
    wt_transpose_kernel<<<(128 * 128 + 255) / 256, 256, 0, stream>>>(W3, Wt3, 128);

    // ---- 1. bucket partition (no global atomics) ----
    coarse_hist_kernel<<<NBLK, 256, 0, stream>>>(src, dst, cntD, cntS, E, NBKT);
    scan_block_sums<<<NBsc, 256, 0, stream>>>(cntD, bsums, nmat);
    scan_bsums<<<1, 256, 0, stream>>>(bsums, NBsc);
    scan_apply<<<NBsc, 256, 0, stream>>>(cntD, bsums, cntD, nmat);
    scan_block_sums<<<NBsc, 256, 0, stream>>>(cntS, bsums, nmat);
    scan_bsums<<<1, 256, 0, stream>>>(bsums, NBsc);
    scan_apply<<<NBsc, 256, 0, stream>>>(cntS, bsums, cntS, nmat);
    scatter_kernel<<<NBLK, 256, 0, stream>>>(src, dst, cntD, cntS, pairs, sbuf, E, NBKT);

    // ---- 2. degrees / CSR / norms / prescaled features ----
    bucket_deg_kernel<<<NBKT, 256, 0, stream>>>(sbuf, cntS, deg_out_i, N, E, NBKT);
    bucket_csr_kernel<<<NBKT, 256, 0, stream>>>(
        pairs, cntD, row_start, deg_in_i, csr_src, N, E, NBKT);
    norm_kernel<<<(2 * N + 255) / 256, 256, 0, stream>>>(deg_out_i, norm_out, 2 * N);
    cvt_slice_kernel<<<(8 * N + 255) / 256, 256, 0, stream>>>(
        feats_node, norm_out, feats16s, N);

    const int gemm_grid = (N + 127) / 128;
    const int C64 = (N + 255) / 256;
    const int C128 = (N + 127) / 128;

    // ---- 3. layer 1 (FIN=64) ----
    slice_agg_kernel<8><<<C64 * 8, 256, 0, stream>>>(
        feats16s, row_start, deg_in_i, csr_src, norm_in, agg16s, q, C64, N);
    gemm_mfma_kernel<64, true, true><<<gemm_grid, 256, 0, stream>>>(
        agg16s, Wt1, b1, norm_out, x16s, N);

    // ---- 4. layer 2 (FIN=128) ----
    slice_agg_kernel<16><<<C128 * 8, 256, 0, stream>>>(
        x16s, row_start, deg_in_i, csr_src, norm_in, agg16s, q + 8, C128, N);
    gemm_mfma_kernel<128, true, true><<<gemm_grid, 256, 0, stream>>>(
        agg16s, Wt2, b2, norm_out, x16s, N);

    // ---- 5. layer 3 (FIN=128, no selu, row-major unscaled out) ----
    slice_agg_kernel<16><<<C128 * 8, 256, 0, stream>>>(
        x16s, row_start, deg_in_i, csr_src, norm_in, agg16s, q + 16, C128, N);
    gemm_mfma_kernel<128, false, false><<<gemm_grid, 256, 0, stream>>>(
        agg16s, Wt3, b3, norm_out, y16, N);

    // ---- 6. readout ----
    graph_starts_kernel<<<(G + 1 + 255) / 256, 256, 0, stream>>>(node2graph, gstart, N, G);
    readout_kernel<<<G, 128, 0, stream>>>(y16, gstart, gsum, G);

    // ---- 7. MLP head ----
    mlp1_kernel<<<G, 256, 0, stream>>>(gsum, feats_graph, L1w, L1b, y1, G);
    mlp2_kernel<<<G, 128, 0, stream>>>(y1, L2w, L2b, y2, G);
    mlp3_kernel<<<(G + 255) / 256, 256, 0, stream>>>(y2, L3w, L3b, out, G);
}

// Round 9
// 548.893 us; speedup vs baseline: 1.3329x; 1.3329x over previous
//
#include <hip/hip_runtime.h>
#include <math.h>

#define SELU_ALPHA 1.6732632423543772f
#define SELU_SCALE 1.0507009873554805f

#define NBLK 512          // partition blocks (E divides exactly: 512*3125)
#define MAXBKT 512        // static LDS sizing; actual NBKT = ceil(N/256)

typedef __attribute__((ext_vector_type(8))) short bf16x8;
typedef __attribute__((ext_vector_type(4))) float f32x4;

__device__ __forceinline__ float selu_f(float x) {
    return SELU_SCALE * (x > 0.f ? x : SELU_ALPHA * expm1f(x));
}

__device__ __forceinline__ float bf2f(unsigned short u) {
    return __uint_as_float(((unsigned)u) << 16);
}
__device__ __forceinline__ unsigned short f2bf(float f) {
    unsigned u = __float_as_uint(f);
    unsigned r = (u + 0x7fffu + ((u >> 16) & 1u)) >> 16;
    return (unsigned short)r;
}

__global__ void norm_kernel(const int* __restrict__ deg, float* __restrict__ norm, int n) {
    int i = blockIdx.x * blockDim.x + threadIdx.x;
    if (i >= n) return;
    norm[i] = 1.f / sqrtf(fmaxf((float)deg[i], 1.f));
}

// ---- exclusive scan (3 kernels), in-place safe ----
#define SCAN_B 1024

__global__ __launch_bounds__(256) void scan_block_sums(const int* __restrict__ in,
                                                       int* __restrict__ bsums, int n) {
    __shared__ int s[256];
    int b = blockIdx.x, t = threadIdx.x;
    int base = b * SCAN_B;
    int sum = 0;
    for (int i = t; i < SCAN_B; i += 256) {
        int idx = base + i;
        sum += (idx < n) ? in[idx] : 0;
    }
    s[t] = sum; __syncthreads();
    for (int off = 128; off > 0; off >>= 1) {
        if (t < off) s[t] += s[t + off];
        __syncthreads();
    }
    if (t == 0) bsums[b] = s[0];
}

__global__ __launch_bounds__(256) void scan_bsums(int* __restrict__ bsums, int nb) {
    __shared__ int s[256];
    __shared__ int carry_s;
    int t = threadIdx.x;
    if (t == 0) carry_s = 0;
    __syncthreads();
    for (int base = 0; base < nb; base += 256) {
        int idx = base + t;
        int v = (idx < nb) ? bsums[idx] : 0;
        s[t] = v; __syncthreads();
        for (int off = 1; off < 256; off <<= 1) {
            int x = (t >= off) ? s[t - off] : 0;
            __syncthreads();
            s[t] += x;
            __syncthreads();
        }
        int incl = s[t];
        int excl = incl - v;
        int c = carry_s;
        __syncthreads();
        if (idx < nb) bsums[idx] = c + excl;
        if (t == 255) carry_s = c + incl;
        __syncthreads();
    }
}

__global__ __launch_bounds__(256) void scan_apply(const int* __restrict__ in,
                                                  const int* __restrict__ boffs,
                                                  int* __restrict__ out, int n) {
    __shared__ int s[256];
    int b = blockIdx.x, t = threadIdx.x;
    int idx0 = b * SCAN_B + t * 4;
    int v[4]; int tsum = 0;
    #pragma unroll
    for (int k = 0; k < 4; ++k) {
        int idx = idx0 + k;
        v[k] = (idx < n) ? in[idx] : 0;
        tsum += v[k];
    }
    s[t] = tsum; __syncthreads();
    for (int off = 1; off < 256; off <<= 1) {
        int x = (t >= off) ? s[t - off] : 0;
        __syncthreads();
        s[t] += x;
        __syncthreads();
    }
    int run = s[t] - tsum + boffs[b];
    #pragma unroll
    for (int k = 0; k < 4; ++k) {
        int idx = idx0 + k;
        if (idx < n) out[idx] = run;
        run += v[k];
    }
}

// ---- K1: per-block coarse histograms of dst>>8 and src>>8 (LDS atomics only) ----
__global__ __launch_bounds__(256) void coarse_hist_kernel(
        const int* __restrict__ src, const int* __restrict__ dst,
        int* __restrict__ cntD, int* __restrict__ cntS, int E, int nbkt) {
    __shared__ int hD[MAXBKT];
    __shared__ int hS[MAXBKT];
    int bb = blockIdx.x, t = threadIdx.x;
    for (int k = t; k < MAXBKT; k += 256) { hD[k] = 0; hS[k] = 0; }
    __syncthreads();
    int chunk = E / NBLK;                 // exact
    int beg = bb * chunk, end = beg + chunk;
    for (int i = beg + t; i < end; i += 256) {
        atomicAdd(&hD[((unsigned)dst[i]) >> 8], 1);
        atomicAdd(&hS[((unsigned)src[i]) >> 8], 1);
    }
    __syncthreads();
    for (int k = t; k < nbkt; k += 256) {
        cntD[k * NBLK + bb] = hD[k];
        cntS[k * NBLK + bb] = hS[k];
    }
}

// ---- K2: scatter edges into dst-buckets (pairs) and src values into src-buckets ----
__global__ __launch_bounds__(256) void scatter_kernel(
        const int* __restrict__ src, const int* __restrict__ dst,
        const int* __restrict__ cntD, const int* __restrict__ cntS,
        uint2* __restrict__ pairs, int* __restrict__ sbuf, int E, int nbkt) {
    __shared__ int cD[MAXBKT];
    __shared__ int cS[MAXBKT];
    int bb = blockIdx.x, t = threadIdx.x;
    for (int k = t; k < nbkt; k += 256) {
        cD[k] = cntD[k * NBLK + bb];
        cS[k] = cntS[k * NBLK + bb];
    }
    __syncthreads();
    int chunk = E / NBLK;
    int beg = bb * chunk, end = beg + chunk;
    for (int i = beg + t; i < end; i += 256) {
        unsigned s = (unsigned)src[i], d = (unsigned)dst[i];
        int pD = atomicAdd(&cD[d >> 8], 1);
        pairs[pD] = make_uint2(s, d);
        int pS = atomicAdd(&cS[s >> 8], 1);
        sbuf[pS] = (int)s;
    }
}

// ---- K3a: per-bucket exact histogram of src values -> deg_out ----
__global__ __launch_bounds__(256) void bucket_deg_kernel(
        const int* __restrict__ sbuf, const int* __restrict__ cntS,
        int* __restrict__ deg_out, int N, int E, int nbkt) {
    __shared__ int hist[256];
    int b = blockIdx.x, t = threadIdx.x;
    int base = cntS[b * NBLK];
    int end = (b + 1 < nbkt) ? cntS[(b + 1) * NBLK] : E;
    hist[t] = 0; __syncthreads();
    for (int i = base + t; i < end; i += 256)
        atomicAdd(&hist[sbuf[i] & 255], 1);
    __syncthreads();
    int node = (b << 8) + t;
    if (node < N) deg_out[node] = hist[t];
}

// ---- K3b: per-bucket CSR build: row_start, deg_in, csr_src ----
__global__ __launch_bounds__(256) void bucket_csr_kernel(
        const uint2* __restrict__ pairs, const int* __restrict__ cntD,
        int* __restrict__ row_start, int* __restrict__ deg_in,
        int* __restrict__ csr_src, int N, int E, int nbkt) {
    __shared__ int hist[256];
    __shared__ int sc[256];
    __shared__ int cur[256];
    int b = blockIdx.x, t = threadIdx.x;
    int base = cntD[b * NBLK];
    int end = (b + 1 < nbkt) ? cntD[(b + 1) * NBLK] : E;
    hist[t] = 0; __syncthreads();
    for (int i = base + t; i < end; i += 256)
        atomicAdd(&hist[pairs[i].y & 255], 1);
    __syncthreads();
    int v = hist[t];
    sc[t] = v; __syncthreads();
    for (int off = 1; off < 256; off <<= 1) {
        int x = (t >= off) ? sc[t - off] : 0;
        __syncthreads();
        sc[t] += x;
        __syncthreads();
    }
    int ex = sc[t] - v;                  // exclusive in-bucket offset
    cur[t] = base + ex;
    int node = (b << 8) + t;
    if (node < N) { row_start[node] = base + ex; deg_in[node] = v; }
    __syncthreads();
    for (int i = base + t; i < end; i += 256) {
        uint2 p = pairs[i];
        int pos = atomicAdd(&cur[p.y & 255], 1);
        csr_src[pos] = (int)p.x;
    }
}

// ---- prep: feats [N][64] fp32 -> row-major bf16 [N][64], prescaled by norm_out ----
__global__ void cvt_feats_kernel(const float* __restrict__ feats,
                                 const float* __restrict__ norm_out,
                                 unsigned short* __restrict__ outp, int N) {
    int i = blockIdx.x * blockDim.x + threadIdx.x;   // i = n*8 + chunk
    if (i >= 8 * N) return;
    int n = i >> 3, c = i & 7;
    float no = norm_out[n];
    const float* fp = feats + (size_t)n * 64 + c * 8;
    float4 a = *reinterpret_cast<const float4*>(fp);
    float4 b = *reinterpret_cast<const float4*>(fp + 4);
    unsigned short o[8] = { f2bf(a.x * no), f2bf(a.y * no), f2bf(a.z * no), f2bf(a.w * no),
                            f2bf(b.x * no), f2bf(b.y * no), f2bf(b.z * no), f2bf(b.w * no) };
    *reinterpret_cast<float4*>(outp + (size_t)n * 64 + c * 8) = *reinterpret_cast<float4*>(o);
}

// ---- prep: W [K][128] fp32 -> Wt [128][K] bf16 ----
__global__ void wt_transpose_kernel(const float* __restrict__ W, unsigned short* __restrict__ Wt,
                                    int K) {
    int i = blockIdx.x * blockDim.x + threadIdx.x;
    if (i >= 128 * K) return;
    int col = i / K, k = i % K;
    Wt[i] = f2bf(W[k * 128 + col]);
}

// ---- prep: fp32 -> bf16 elementwise (x4) ----
__global__ void cvt_bf16_kernel(const float* __restrict__ in, unsigned short* __restrict__ out,
                                int n4) {
    int i = blockIdx.x * blockDim.x + threadIdx.x;
    if (i >= n4) return;
    float4 v = reinterpret_cast<const float4*>(in)[i];
    unsigned short o[4] = { f2bf(v.x), f2bf(v.y), f2bf(v.z), f2bf(v.w) };
    reinterpret_cast<uint2*>(out)[i] = *reinterpret_cast<uint2*>(o);
}

// ---- gather-aggregate with shuffle-broadcast index ILP ----
// TPG lanes per node; per chunk the TPG lanes cooperatively load TPG indices
// (one coalesced read), then __shfl broadcasts each -> all gathers independent.
// agg16[n] = f2bf(norm_in[n] * sum_e x16[csr_src[e]])   (x16 prescaled by norm_out)
template<int TPG, int FIN>   // TPG = FIN/8
__global__ __launch_bounds__(256) void csr_agg_kernel(
        const unsigned short* __restrict__ x, const int* __restrict__ row_start,
        const int* __restrict__ deg, const int* __restrict__ csr_src,
        const float* __restrict__ norm_in,
        unsigned short* __restrict__ agg, int N) {
    const int GPB = 256 / TPG;
    int g = threadIdx.x / TPG;
    int j = threadIdx.x % TPG;
    int n = blockIdx.x * GPB + g;
    if (n >= N) return;
    const int lane = threadIdx.x & 63;
    const int gbase = lane & ~(TPG - 1);   // group base lane within wave
    int beg = row_start[n];
    int end = beg + deg[n];
    float acc[8] = {0.f, 0.f, 0.f, 0.f, 0.f, 0.f, 0.f, 0.f};
    for (int c = beg; c < end; c += TPG) {
        int myIdx = (c + j < end) ? csr_src[c + j] : 0;
        int cnt = end - c;                 // uniform within group
        float4 v[TPG];
        #pragma unroll
        for (int t = 0; t < TPG; ++t) {
            if (t < cnt) {
                int s = __shfl(myIdx, gbase + t, 64);
                v[t] = *reinterpret_cast<const float4*>(&x[(size_t)s * FIN + j * 8]);
            }
        }
        #pragma unroll
        for (int t = 0; t < TPG; ++t) {
            if (t < cnt) {
                const unsigned short* u = reinterpret_cast<const unsigned short*>(&v[t]);
                #pragma unroll
                for (int k = 0; k < 8; ++k) acc[k] += bf2f(u[k]);
            }
        }
    }
    float nin = norm_in[n];
    unsigned short ov[8];
    #pragma unroll
    for (int k = 0; k < 8; ++k) ov[k] = f2bf(acc[k] * nin);
    *reinterpret_cast<float4*>(&agg[(size_t)n * FIN + j * 8]) = *reinterpret_cast<float4*>(ov);
}

// ---- MFMA node GEMM (128x128 tile, 4 waves, 16x16x32 bf16) ----
// out[n][col] = act(agg16[n] @ Wt^T + b) [* norm_out[n] if SCALE_OUT], bf16 row-major.
template<int FIN, bool SELU, bool SCALE_OUT>
__global__ __launch_bounds__(256, 2) void gemm_mfma_kernel(
        const unsigned short* __restrict__ agg16,  // [N][FIN] bf16
        const unsigned short* __restrict__ Wt,     // [128][FIN] bf16
        const float* __restrict__ b,
        const float* __restrict__ norm_out,
        unsigned short* __restrict__ out,          // [N][128] bf16
        int N) {
    const int PAD = 8;
    const int LDA = FIN + PAD;
    const int CH = FIN / 8;
    __shared__ unsigned short sA[128 * LDA];
    __shared__ unsigned short sW[128 * LDA];
    const int tid = threadIdx.x;
    const int wave = tid >> 6, lane = tid & 63;
    const int wr = (wave >> 1) * 64;
    const int wc = (wave & 1) * 64;
    const int n0 = blockIdx.x * 128;

    for (int i = tid; i < 128 * CH; i += 256) {
        int col = i / CH, kc = i % CH;
        *reinterpret_cast<float4*>(&sW[col * LDA + kc * 8]) =
            *reinterpret_cast<const float4*>(&Wt[col * FIN + kc * 8]);
    }
    for (int i = tid; i < 128 * CH; i += 256) {
        int node = i / CH, kc = i % CH;
        int n = n0 + node;
        float4 v = make_float4(0.f, 0.f, 0.f, 0.f);
        if (n < N)
            v = *reinterpret_cast<const float4*>(&agg16[(size_t)n * FIN + kc * 8]);
        *reinterpret_cast<float4*>(&sA[node * LDA + kc * 8]) = v;
    }
    __syncthreads();

    const int l16 = lane & 15;
    const int lk = (lane >> 4) * 8;
    f32x4 acc[4][4];
    #pragma unroll
    for (int mi = 0; mi < 4; ++mi)
        #pragma unroll
        for (int ci = 0; ci < 4; ++ci)
            acc[mi][ci] = (f32x4){0.f, 0.f, 0.f, 0.f};

    #pragma unroll
    for (int k0 = 0; k0 < FIN; k0 += 32) {
        bf16x8 a[4], w[4];
        #pragma unroll
        for (int mi = 0; mi < 4; ++mi)
            a[mi] = *reinterpret_cast<const bf16x8*>(&sA[(wr + mi * 16 + l16) * LDA + k0 + lk]);
        #pragma unroll
        for (int ci = 0; ci < 4; ++ci)
            w[ci] = *reinterpret_cast<const bf16x8*>(&sW[(wc + ci * 16 + l16) * LDA + k0 + lk]);
        #pragma unroll
        for (int mi = 0; mi < 4; ++mi)
            #pragma unroll
            for (int ci = 0; ci < 4; ++ci)
                acc[mi][ci] = __builtin_amdgcn_mfma_f32_16x16x32_bf16(
                    a[mi], w[ci], acc[mi][ci], 0, 0, 0);
    }

    // D frag: col = lane&15, row = (lane>>4)*4 + r
    const int rbase = (lane >> 4) * 4;
    #pragma unroll
    for (int ci = 0; ci < 4; ++ci) {
        int col = wc + ci * 16 + l16;
        float bias = b[col];
        #pragma unroll
        for (int mi = 0; mi < 4; ++mi) {
            #pragma unroll
            for (int r = 0; r < 4; ++r) {
                int n = n0 + wr + mi * 16 + rbase + r;
                if (n < N) {
                    float v = acc[mi][ci][r] + bias;
                    if (SELU) v = selu_f(v);
                    if (SCALE_OUT) v *= norm_out[n];
                    out[(size_t)n * 128 + col] = f2bf(v);
                }
            }
        }
    }
}

// ---- graph range starts (node2graph sorted) ----
__global__ void graph_starts_kernel(const int* __restrict__ n2g, int* __restrict__ gstart,
                                    int N, int G) {
    int g = blockIdx.x * blockDim.x + threadIdx.x;
    if (g > G) return;
    int lo = 0, hi = N;
    while (lo < hi) {
        int mid = (lo + hi) >> 1;
        if (n2g[mid] < g) lo = mid + 1; else hi = mid;
    }
    gstart[g] = lo;
}

// ---- readout from bf16 y (row-major) ----
__global__ __launch_bounds__(128) void readout_kernel(
        const unsigned short* __restrict__ y, const int* __restrict__ gstart,
        float* __restrict__ gsum, int G) {
    int g = blockIdx.x;
    int o = threadIdx.x;
    if (g >= G) return;
    int beg = gstart[g], end = gstart[g + 1];
    float acc = 0.f;
    for (int n = beg; n < end; ++n)
        acc += bf2f(y[(size_t)n * 128 + o]);
    gsum[(size_t)g * 128 + o] = acc;
}

// ---- MLP head: 16 graphs per block, bf16 W staged in LDS, fp32 accumulate ----
__global__ __launch_bounds__(256) void mlp1_kernel(
        const float* __restrict__ gsum, const float* __restrict__ fg,
        const unsigned short* __restrict__ W16,    // [131][256] bf16
        const float* __restrict__ b,
        float* __restrict__ y1, int G) {
    __shared__ unsigned short sW[131 * 256];
    __shared__ float sIn[16][132];
    int tid = threadIdx.x;
    for (int i = tid; i < 131 * 256 / 2; i += 256)
        reinterpret_cast<unsigned*>(sW)[i] = reinterpret_cast<const unsigned*>(W16)[i];
    int g0 = blockIdx.x * 16;
    for (int i = tid; i < 16 * 131; i += 256) {
        int g = i / 131, k = i - g * 131;
        float v = 0.f;
        if (g0 + g < G)
            v = (k < 128) ? gsum[(size_t)(g0 + g) * 128 + k]
                          : fg[(size_t)(g0 + g) * 3 + (k - 128)];
        sIn[g][k] = v;
    }
    __syncthreads();
    float bias = b[tid];
    for (int g = 0; g < 16; ++g) {
        if (g0 + g >= G) break;
        float acc = bias;
        #pragma unroll 8
        for (int k = 0; k < 131; ++k)
            acc += sIn[g][k] * bf2f(sW[k * 256 + tid]);
        y1[(size_t)(g0 + g) * 256 + tid] = selu_f(acc);
    }
}

__global__ __launch_bounds__(256) void mlp2_kernel(
        const float* __restrict__ y1,
        const unsigned short* __restrict__ W16,    // [256][128] bf16
        const float* __restrict__ b,
        float* __restrict__ y2, int G) {
    __shared__ unsigned short sW[256 * 128];
    __shared__ float sIn[16][256];
    int tid = threadIdx.x;
    for (int i = tid; i < 256 * 128 / 2; i += 256)
        reinterpret_cast<unsigned*>(sW)[i] = reinterpret_cast<const unsigned*>(W16)[i];
    int g0 = blockIdx.x * 16;
    for (int i = tid; i < 16 * 256; i += 256) {
        int g = i >> 8, k = i & 255;
        sIn[g][k] = (g0 + g < G) ? y1[(size_t)(g0 + g) * 256 + k] : 0.f;
    }
    __syncthreads();
    int o = tid & 127;
    int half = tid >> 7;           // handles graphs half*8 .. half*8+7
    float bias = b[o];
    for (int gg = 0; gg < 8; ++gg) {
        int g = half * 8 + gg;
        if (g0 + g >= G) break;
        float acc = bias;
        #pragma unroll 8
        for (int k = 0; k < 256; ++k)
            acc += sIn[g][k] * bf2f(sW[k * 128 + o]);
        y2[(size_t)(g0 + g) * 128 + o] = selu_f(acc);
    }
}

__global__ void mlp3_kernel(const float* __restrict__ y2, const float* __restrict__ W,
                            const float* __restrict__ b, float* __restrict__ out, int G) {
    int g = blockIdx.x * blockDim.x + threadIdx.x;
    if (g >= G) return;
    const float* in = y2 + (size_t)g * 128;
    float acc = b[0];
    #pragma unroll 8
    for (int k = 0; k < 128; ++k) acc += in[k] * W[k];
    out[g] = acc;
}

extern "C" void kernel_launch(void* const* d_in, const int* in_sizes, int n_in,
                              void* d_out, int out_size, void* d_ws, size_t ws_size,
                              hipStream_t stream) {
    const float* feats_node  = (const float*)d_in[0];
    const float* feats_graph = (const float*)d_in[1];
    const int*   src         = (const int*)d_in[2];
    const int*   dst         = (const int*)d_in[3];
    const int*   node2graph  = (const int*)d_in[4];
    const float* W1 = (const float*)d_in[5];
    const float* b1 = (const float*)d_in[6];
    const float* W2 = (const float*)d_in[7];
    const float* b2 = (const float*)d_in[8];
    const float* W3 = (const float*)d_in[9];
    const float* b3 = (const float*)d_in[10];
    const float* L1w = (const float*)d_in[11];
    const float* L1b = (const float*)d_in[12];
    const float* L2w = (const float*)d_in[13];
    const float* L2b = (const float*)d_in[14];
    const float* L3w = (const float*)d_in[15];
    const float* L3b = (const float*)d_in[16];

    const int N = in_sizes[0] / 64;
    const int G = in_sizes[1] / 3;
    const int E = in_sizes[2];
    const int NBKT = (N + 255) >> 8;
    const int nmat = NBKT * NBLK;
    const int NBsc = (nmat + SCAN_B - 1) / SCAN_B;

    // ---- workspace layout ----
    int* iws = (int*)d_ws;
    int* deg_out_i = iws;                      // N
    int* deg_in_i  = deg_out_i + N;            // N
    int* row_start = deg_in_i + N;             // N
    int* bsums     = row_start + N;            // 512
    int* gstart    = bsums + 512;              // G+8
    int* cntD      = gstart + (G + 8);         // nmat
    int* cntS      = cntD + nmat;              // nmat
    int* csr_src   = cntS + nmat;              // E

    float* norm_out = (float*)(csr_src + E);   // N
    float* norm_in  = norm_out + N;            // N  (adjacent: norm_kernel does 2N)

    unsigned short* feats16 = (unsigned short*)(norm_in + N);     // [N][64]
    unsigned short* x16     = feats16 + (size_t)N * 64;           // [N][128]
    unsigned short* agg16   = x16 + (size_t)N * 128;              // [N][128]
    unsigned short* y16     = agg16 + (size_t)N * 128;            // [N][128]
    unsigned short* Wt1     = y16 + (size_t)N * 128;              // 128*64
    unsigned short* Wt2     = Wt1 + 128 * 64;                     // 128*128
    unsigned short* Wt3     = Wt2 + 128 * 128;                    // 128*128
    unsigned short* L1w16   = Wt3 + 128 * 128;                    // 131*256
    unsigned short* L2w16   = L1w16 + 131 * 256;                  // 256*128

    float* gsum = (float*)(L2w16 + 256 * 128); // G*128
    float* y1   = gsum + (size_t)G * 128;      // G*256
    float* y2   = y1 + (size_t)G * 256;        // G*128

    // pairs/sbuf alias y16 (dead until layer-3 output)
    uint2* pairs = (uint2*)(((uintptr_t)y16 + 15) & ~(uintptr_t)15);  // E uint2
    int*   sbuf  = (int*)(pairs + E);                                  // E ints

    float* out = (float*)d_out;

    // ---- 0. weight prep ----
    wt_transpose_kernel<<<(128 * 64 + 255) / 256, 256, 0, stream>>>(W1, Wt1, 64);
    wt_transpose_kernel<<<(128 * 128 + 255) / 256, 256, 0, stream>>>(W2, Wt2, 128);
    wt_transpose_kernel<<<(128 * 128 + 255) / 256, 256, 0, stream>>>(W3, Wt3, 128);
    cvt_bf16_kernel<<<(131 * 256 / 4 + 255) / 256, 256, 0, stream>>>(L1w, L1w16, 131 * 256 / 4);
    cvt_bf16_kernel<<<(256 * 128 / 4 + 255) / 256, 256, 0, stream>>>(L2w, L2w16, 256 * 128 / 4);

    // ---- 1. bucket partition (no global atomics) ----
    coarse_hist_kernel<<<NBLK, 256, 0, stream>>>(src, dst, cntD, cntS, E, NBKT);
    scan_block_sums<<<NBsc, 256, 0, stream>>>(cntD, bsums, nmat);
    scan_bsums<<<1, 256, 0, stream>>>(bsums, NBsc);
    scan_apply<<<NBsc, 256, 0, stream>>>(cntD, bsums, cntD, nmat);
    scan_block_sums<<<NBsc, 256, 0, stream>>>(cntS, bsums, nmat);
    scan_bsums<<<1, 256, 0, stream>>>(bsums, NBsc);
    scan_apply<<<NBsc, 256, 0, stream>>>(cntS, bsums, cntS, nmat);
    scatter_kernel<<<NBLK, 256, 0, stream>>>(src, dst, cntD, cntS, pairs, sbuf, E, NBKT);

    // ---- 2. degrees / CSR / norms / prescaled features ----
    bucket_deg_kernel<<<NBKT, 256, 0, stream>>>(sbuf, cntS, deg_out_i, N, E, NBKT);
    bucket_csr_kernel<<<NBKT, 256, 0, stream>>>(
        pairs, cntD, row_start, deg_in_i, csr_src, N, E, NBKT);
    norm_kernel<<<(2 * N + 255) / 256, 256, 0, stream>>>(deg_out_i, norm_out, 2 * N);
    cvt_feats_kernel<<<(8 * N + 255) / 256, 256, 0, stream>>>(
        feats_node, norm_out, feats16, N);

    const int gemm_grid = (N + 127) / 128;

    // ---- 3. layer 1 (FIN=64) ----
    csr_agg_kernel<8, 64><<<(N + 31) / 32, 256, 0, stream>>>(
        feats16, row_start, deg_in_i, csr_src, norm_in, agg16, N);
    gemm_mfma_kernel<64, true, true><<<gemm_grid, 256, 0, stream>>>(
        agg16, Wt1, b1, norm_out, x16, N);

    // ---- 4. layer 2 (FIN=128) ----
    csr_agg_kernel<16, 128><<<(N + 15) / 16, 256, 0, stream>>>(
        x16, row_start, deg_in_i, csr_src, norm_in, agg16, N);
    gemm_mfma_kernel<128, true, true><<<gemm_grid, 256, 0, stream>>>(
        agg16, Wt2, b2, norm_out, x16, N);

    // ---- 5. layer 3 (FIN=128, no selu, unscaled out for readout) ----
    csr_agg_kernel<16, 128><<<(N + 15) / 16, 256, 0, stream>>>(
        x16, row_start, deg_in_i, csr_src, norm_in, agg16, N);
    gemm_mfma_kernel<128, false, false><<<gemm_grid, 256, 0, stream>>>(
        agg16, Wt3, b3, norm_out, y16, N);

    // ---- 6. readout ----
    graph_starts_kernel<<<(G + 1 + 255) / 256, 256, 0, stream>>>(node2graph, gstart, N, G);
    readout_kernel<<<G, 128, 0, stream>>>(y16, gstart, gsum, G);

    // ---- 7. MLP head ----
    mlp1_kernel<<<(G + 15) / 16, 256, 0, stream>>>(gsum, feats_graph, L1w16, L1b, y1, G);
    mlp2_kernel<<<(G + 15) / 16, 256, 0, stream>>>(y1, L2w16, L2b, y2, G);
    mlp3_kernel<<<(G + 255) / 256, 256, 0, stream>>>(y2, L3w, L3b, out, G);
}